// Round 1
// baseline (197.745 us; speedup 1.0000x reference)
//
#include <hip/hip_runtime.h>
#include <math.h>

// SSIM loss: 1 - mean(SSIM(x,y)), 11x11 separable gaussian, VALID padding.
// x,y: fp32 [16,3,512,512] -> 48 channels of 512x512; output map 502x502.
//
// Trick: blur only {p=x+y, q=x-y, p^2, q^2} (4 blurs instead of 5):
//   P=blur(p), Q=blur(q), S2=blur(p^2), T2=blur(q^2)
//   luminance num/den = (P^2-Q^2+2C1)/(P^2+Q^2+2C1)
//   contrast  num/den = (S2-T2-(P^2-Q^2)+2C2)/(S2+T2-(P^2+Q^2)+2C2)

#define HH 512
#define WW 512
#define NCH 48
#define OUTD 502
#define SEGS 16
#define SEG_ROWS 32
#define ITERS 44            // 4*11 >= SEG_ROWS + 10
#define NBLK (NCH * SEGS)   // 768

#define TWO_C1 13.0050f     // 2*(0.01*255)^2
#define TWO_C2 117.0450f    // 2*(0.03*255)^2

struct GW { float g[11]; };

__global__ __launch_bounds__(256, 2)
void ssim_main(const float* __restrict__ x, const float* __restrict__ y,
               float* __restrict__ partial, GW gw) {
    const int tid = threadIdx.x;
    const int bid = blockIdx.x;
    const int ch  = bid >> 4;        // / SEGS
    const int seg = bid & (SEGS - 1);
    const int r0  = seg * SEG_ROWS;
    const int nrows = min(SEG_ROWS, OUTD - r0);

    int j = 2 * tid;
    const bool jvalid = (j < OUTD);
    if (!jvalid) j = 500;            // safe clamp; contribution masked below

    const size_t chbase = (size_t)ch * (HH * WW);
    const float* xb = x + chbase + j;
    const float* yb = y + chbase + j;

    // ring of horizontally-blurred rows: 4 quantities x 11 rows x 2 cols
    float rP[11][2], rQ[11][2], rS[11][2], rT[11][2];
    float acc = 0.0f;

    for (int base = 0; base < ITERS; base += 11) {
        #pragma unroll
        for (int u = 0; u < 11; ++u) {
            const int it = base + u;
            const int r  = min(r0 + it, HH - 1);
            const float2* xr = (const float2*)(xb + (size_t)r * WW);
            const float2* yr = (const float2*)(yb + (size_t)r * WW);

            float p[12], q[12];
            #pragma unroll
            for (int d = 0; d < 6; ++d) {
                float2 xv = xr[d];
                float2 yv = yr[d];
                p[2*d]   = xv.x + yv.x;  q[2*d]   = xv.x - yv.x;
                p[2*d+1] = xv.y + yv.y;  q[2*d+1] = xv.y - yv.y;
            }
            float s[12], t[12];
            #pragma unroll
            for (int d = 0; d < 12; ++d) { s[d] = p[d]*p[d]; t[d] = q[d]*q[d]; }

            float hp0=0.f,hq0=0.f,hs0=0.f,ht0=0.f;
            float hp1=0.f,hq1=0.f,hs1=0.f,ht1=0.f;
            #pragma unroll
            for (int k = 0; k < 11; ++k) {
                const float w = gw.g[k];
                hp0 = fmaf(w, p[k],   hp0);  hq0 = fmaf(w, q[k],   hq0);
                hs0 = fmaf(w, s[k],   hs0);  ht0 = fmaf(w, t[k],   ht0);
                hp1 = fmaf(w, p[k+1], hp1);  hq1 = fmaf(w, q[k+1], hq1);
                hs1 = fmaf(w, s[k+1], hs1);  ht1 = fmaf(w, t[k+1], ht1);
            }
            rP[u][0]=hp0; rP[u][1]=hp1;  rQ[u][0]=hq0; rQ[u][1]=hq1;
            rS[u][0]=hs0; rS[u][1]=hs1;  rT[u][0]=ht0; rT[u][1]=ht1;

            const int il = it - 10;      // local output row
            if (il >= 0 && il < nrows && jvalid) {
                float P0=0.f,Q0=0.f,S0=0.f,T0=0.f;
                float P1=0.f,Q1=0.f,S1=0.f,T1=0.f;
                #pragma unroll
                for (int k = 0; k < 11; ++k) {
                    const int sl = (u + 1 + k) % 11;   // static after unroll
                    const float w = gw.g[k];
                    P0=fmaf(w,rP[sl][0],P0); Q0=fmaf(w,rQ[sl][0],Q0);
                    S0=fmaf(w,rS[sl][0],S0); T0=fmaf(w,rT[sl][0],T0);
                    P1=fmaf(w,rP[sl][1],P1); Q1=fmaf(w,rQ[sl][1],Q1);
                    S1=fmaf(w,rS[sl][1],S1); T1=fmaf(w,rT[sl][1],T1);
                }
                // col 0
                {
                    float A = P0*P0, B = Q0*Q0;
                    float u1 = A - B, u2 = A + B;
                    float ln_ = u1 + TWO_C1;
                    float ld_ = u2 + TWO_C1;
                    float cn_ = (S0 - T0) - u1 + TWO_C2;
                    float cd_ = (S0 + T0) - u2 + TWO_C2;
                    acc += (ln_ * cn_) / (ld_ * cd_);
                }
                // col 1
                {
                    float A = P1*P1, B = Q1*Q1;
                    float u1 = A - B, u2 = A + B;
                    float ln_ = u1 + TWO_C1;
                    float ld_ = u2 + TWO_C1;
                    float cn_ = (S1 - T1) - u1 + TWO_C2;
                    float cd_ = (S1 + T1) - u2 + TWO_C2;
                    acc += (ln_ * cn_) / (ld_ * cd_);
                }
            }
        }
    }

    // block reduction: wave shfl, then LDS across the 4 waves
    #pragma unroll
    for (int off = 32; off > 0; off >>= 1) acc += __shfl_down(acc, off);
    __shared__ float sh[4];
    const int wid  = tid >> 6;
    const int lane = tid & 63;
    if (lane == 0) sh[wid] = acc;
    __syncthreads();
    if (tid == 0) partial[bid] = sh[0] + sh[1] + sh[2] + sh[3];
}

__global__ void ssim_reduce(const float* __restrict__ partial,
                            float* __restrict__ out) {
    double s = 0.0;
    for (int i = threadIdx.x; i < NBLK; i += 256) s += (double)partial[i];
    #pragma unroll
    for (int off = 32; off > 0; off >>= 1) s += __shfl_down(s, off);
    __shared__ double sh[4];
    const int wid  = threadIdx.x >> 6;
    const int lane = threadIdx.x & 63;
    if (lane == 0) sh[wid] = s;
    __syncthreads();
    if (threadIdx.x == 0) {
        double tot = sh[0] + sh[1] + sh[2] + sh[3];
        double cnt = (double)NCH * (double)OUTD * (double)OUTD;
        out[0] = (float)(1.0 - tot / cnt);
    }
}

extern "C" void kernel_launch(void* const* d_in, const int* in_sizes, int n_in,
                              void* d_out, int out_size, void* d_ws, size_t ws_size,
                              hipStream_t stream) {
    const float* x = (const float*)d_in[0];
    const float* y = (const float*)d_in[1];
    // d_in[2] = epoch, unused (dead code in reference)
    float* out = (float*)d_out;
    float* ws  = (float*)d_ws;   // 768 floats of partial sums

    GW gw;
    {
        double v[11], sum = 0.0;
        for (int k = 0; k < 11; ++k) {
            double c = (double)(k - 5);
            v[k] = exp(-(c * c) / 4.5);   // 2*sigma^2 = 4.5
            sum += v[k];
        }
        for (int k = 0; k < 11; ++k) gw.g[k] = (float)(v[k] / sum);
    }

    hipLaunchKernelGGL(ssim_main, dim3(NBLK), dim3(256), 0, stream, x, y, ws, gw);
    hipLaunchKernelGGL(ssim_reduce, dim3(1), dim3(256), 0, stream, ws, out);
}